// Round 4
// baseline (201.536 us; speedup 1.0000x reference)
//
#include <hip/hip_runtime.h>
#include <math.h>

// Problem constants (N=512 Clements mesh, L=512 layers, fixed by reference).
#define NPORT  512
#define NLAYER 512
#define NPAIR  256                      // even/odd layer pairs
#define CHUNK  4                        // layer-pairs per LDS stage
#define NCHUNK (NPAIR / CHUNK)          // 64 chunks
#define PPL    8                        // coefficient planes per pair
#define PLANES (CHUNK * PPL)            // 32 planes per chunk (32 KB)
#define ATTEN  0.9772372209558107f      // sqrt(10^(-0.2/10))

// Async global->LDS DMA, 16B per lane: LDS dst = uniform base + lane*16.
__device__ __forceinline__ void load_lds16(const float4* g, void* l) {
    __builtin_amdgcn_global_load_lds(
        (const __attribute__((address_space(1))) void*)g,
        (__attribute__((address_space(3))) void*)l, 16, 0, 0);
}

// ---------------------------------------------------------------------------
// Coefficient table: per layer-pair p, 8 planes of 64 float4 (one per lane):
//   planes 0..3: even layer 2p,  lane t slot 4t+j (ports 8t+2j, 8t+2j+1)
//   planes 4..7: odd  layer 2p+1, lane t slot 4t+j (ports 8t+2j+1, 8t+2j+2)
// float4 = {cos(th)*A, sin(th)*A, cos(ph), sin(ph)}; invalid slot (odd,255)
// = identity {1,0,1,0}. The odd-layer LEFT-crossing coefficient for lane t
// (slot 4t-1) is lane t-1's plane-7 value (obtained via shfl_up).
// ---------------------------------------------------------------------------
__global__ void coeff_kernel(const float* __restrict__ thetas,
                             const float* __restrict__ phis,
                             const int*   __restrict__ mzi_idx,
                             float4*      __restrict__ table) {
    int tid = blockIdx.x * blockDim.x + threadIdx.x;   // 0 .. NPAIR*8*64-1
    if (tid >= NPAIR * PPL * 64) return;
    int lane  = tid & 63;
    int plane = (tid >> 6) & 7;
    int p     = tid >> 9;

    int layer, slot, port_i;
    bool valid;
    if (plane < 4) {                    // even layer
        layer  = 2 * p;
        slot   = 4 * lane + plane;
        port_i = 2 * slot;
        valid  = true;
    } else {                            // odd layer local slots
        layer  = 2 * p + 1;
        slot   = 4 * lane + (plane - 4);
        port_i = 2 * slot + 1;
        valid  = (2 * slot + 2) < NPORT;   // slot 255 -> ports 511/512
    }

    float4 c = make_float4(1.f, 0.f, 1.f, 0.f);
    if (valid) {
        int m  = mzi_idx[layer * NPORT + port_i];
        float th = thetas[m], ph = phis[m];
        c.x = cosf(th) * ATTEN;
        c.y = sinf(th) * ATTEN;
        c.z = cosf(ph);
        c.w = sinf(ph);
    }
    table[(size_t)(p * PPL + plane) * 64 + lane] = c;
}

// ---------------------------------------------------------------------------
// Mesh propagation. 128 threads = 2 waves/block, one batch row per wave;
// lane t holds ports 8t..8t+7 (complex) in registers. 512 blocks -> 2
// independent blocks per CU: two barrier domains, so one block computes
// while the other drains its DMA (wave-level overlap, m114).
// Chunk of 4 layer-pairs staged in LDS via global_load_lds, double-buffered
// across two distinct __shared__ arrays. All 4 pairs' coefficients are
// ds_read_b128-burst into registers at chunk start (full-chunk prefetch,
// ~128 VGPRs) so compute never waits on a just-issued LDS read.
// ---------------------------------------------------------------------------
struct PairCoef {
    float4 e[4];   // even-layer slots
    float4 o[4];   // odd-layer local slots
};

__global__ __launch_bounds__(128, 1)
void mesh_kernel(const float*  __restrict__ x,
                 const float4* __restrict__ table,
                 float*        __restrict__ out,
                 int B) {
    __shared__ float4 bufA[PLANES][64];   // 32 KB
    __shared__ float4 bufB[PLANES][64];   // 32 KB

    const int lane = threadIdx.x & 63;
    const int wid  = threadIdx.x >> 6;    // 0..1
    const int row  = blockIdx.x * 2 + wid;
    const bool live = row < B;

    // Load 8 consecutive real inputs -> complex state (im = 0).
    const float4* xr =
        (const float4*)(x + (size_t)(live ? row : 0) * NPORT) + lane * 2;
    float4 xa = xr[0], xb = xr[1];
    float sr[8] = {xa.x, xa.y, xa.z, xa.w, xb.x, xb.y, xb.z, xb.w};
    float si[8] = {0.f, 0.f, 0.f, 0.f, 0.f, 0.f, 0.f, 0.f};

    // DMA chunk c's 32 planes into buf; wave w takes planes 16w..16w+15.
    auto stage = [&](int c, float4 (*buf)[64]) {
        const float4* g = table + (size_t)c * (PLANES * 64) + lane;
#pragma unroll
        for (int k = 0; k < PLANES / 2; ++k) {
            int pl = wid * (PLANES / 2) + k;
            load_lds16(g + pl * 64, (void*)&buf[pl][0]);
        }
    };

    // One MZI, both ports lane-local; upper port gets the phase.
    auto mzi = [&](const float4 c, int p0, int p1) {
        float ct = c.x, st = c.y, er = c.z, ei = c.w;
        float ur = ct * sr[p0] + st * sr[p1];
        float ui = ct * si[p0] + st * si[p1];
        float lr = ct * sr[p1] - st * sr[p0];
        float li = ct * si[p1] - st * si[p0];
        sr[p0] = er * ur - ei * ui;
        si[p0] = er * ui + ei * ur;
        sr[p1] = lr;
        si[p1] = li;
    };

    auto computePair = [&](const PairCoef& b) {
        // Even layer: ports (2j, 2j+1), all lane-local.
#pragma unroll
        for (int j = 0; j < 4; ++j) mzi(b.e[j], 2 * j, 2 * j + 1);

        // Odd layer. All 6 shuffles issued up-front on OLD values.
        float hr = __shfl_down(sr[0], 1);     // right neighbor's port 8t+8
        float hi = __shfl_down(si[0], 1);
        float gr = __shfl_up(sr[7], 1);       // left neighbor's port 8t-1
        float gi = __shfl_up(si[7], 1);
        float lc = __shfl_up(b.o[3].x, 1);    // left-crossing ct (slot 4t-1)
        float ls = __shfl_up(b.o[3].y, 1);    // left-crossing st
        float ct4 = (lane > 0) ? lc : 1.f;    // lane 0: port 0 passthrough
        float st4 = (lane > 0) ? ls : 0.f;

        // 3 internal MZIs: ports (2j+1, 2j+2).
#pragma unroll
        for (int j = 0; j < 3; ++j) mzi(b.o[j], 2 * j + 1, 2 * j + 2);

        // Right crossing (upper = local port 7, lower = h): keep upper+phase.
        {
            float ct = b.o[3].x, st = b.o[3].y, er = b.o[3].z, ei = b.o[3].w;
            float ur = ct * sr[7] + st * hr;
            float ui = ct * si[7] + st * hi;
            sr[7] = er * ur - ei * ui;
            si[7] = er * ui + ei * ur;
        }
        // Left crossing (upper = g, lower = local port 0): keep lower.
        {
            float lr = ct4 * sr[0] - st4 * gr;
            float li = ct4 * si[0] - st4 * gi;
            sr[0] = lr;
            si[0] = li;
        }
    };

    auto readPair = [&](const float4 (*buf)[64], int pp) {
        PairCoef b;
#pragma unroll
        for (int j = 0; j < 4; ++j) b.e[j] = buf[pp * PPL + j][lane];
#pragma unroll
        for (int j = 0; j < 4; ++j) b.o[j] = buf[pp * PPL + 4 + j][lane];
        return b;
    };

    // Full-chunk register prefetch: burst all 32 ds_read_b128 first, then
    // compute. Straight-line so the scheduler can issue reads early and let
    // fine-grained lgkmcnt cover the first pair's latency.
    auto computeChunk = [&](const float4 (*buf)[64]) {
        PairCoef c[CHUNK];
#pragma unroll
        for (int pp = 0; pp < CHUNK; ++pp) c[pp] = readPair(buf, pp);
#pragma unroll
        for (int pp = 0; pp < CHUNK; ++pp) computePair(c[pp]);
    };

    stage(0, bufA);
    __syncthreads();

#pragma unroll 1
    for (int c = 0; c < NCHUNK; c += 2) {
        if (c + 1 < NCHUNK) stage(c + 1, bufB);
        computeChunk(bufA);
        __syncthreads();
        if (c + 2 < NCHUNK) stage(c + 2, bufA);
        computeChunk(bufB);
        __syncthreads();
    }

    // Photodetection: |E|^2, vectorized store.
    if (live) {
        float4 o0 = make_float4(sr[0] * sr[0] + si[0] * si[0],
                                sr[1] * sr[1] + si[1] * si[1],
                                sr[2] * sr[2] + si[2] * si[2],
                                sr[3] * sr[3] + si[3] * si[3]);
        float4 o1 = make_float4(sr[4] * sr[4] + si[4] * si[4],
                                sr[5] * sr[5] + si[5] * si[5],
                                sr[6] * sr[6] + si[6] * si[6],
                                sr[7] * sr[7] + si[7] * si[7]);
        float4* op = (float4*)(out + (size_t)row * NPORT) + lane * 2;
        op[0] = o0;
        op[1] = o1;
    }
}

// ---------------------------------------------------------------------------
// Fallback (ws too small for the table): trig inline, slow but correct.
// ---------------------------------------------------------------------------
__global__ __launch_bounds__(64)
void mesh_fallback(const float* __restrict__ x,
                   const float* __restrict__ thetas,
                   const float* __restrict__ phis,
                   const int*   __restrict__ mzi_idx,
                   float*       __restrict__ out) {
    const int lane = threadIdx.x;
    const int row  = blockIdx.x;

    const float4* xr = (const float4*)(x + (size_t)row * NPORT) + lane * 2;
    float4 xa = xr[0], xb = xr[1];
    float sr[8] = {xa.x, xa.y, xa.z, xa.w, xb.x, xb.y, xb.z, xb.w};
    float si[8] = {0.f, 0.f, 0.f, 0.f, 0.f, 0.f, 0.f, 0.f};

    auto mzi = [&](float ct, float st, float er, float ei, int p0, int p1) {
        float ur = ct * sr[p0] + st * sr[p1];
        float ui = ct * si[p0] + st * si[p1];
        float lr = ct * sr[p1] - st * sr[p0];
        float li = ct * si[p1] - st * si[p0];
        sr[p0] = er * ur - ei * ui;
        si[p0] = er * ui + ei * ur;
        sr[p1] = lr;
        si[p1] = li;
    };

    for (int l = 0; l < NLAYER; ++l) {
        if ((l & 1) == 0) {
#pragma unroll
            for (int j = 0; j < 4; ++j) {
                int m = mzi_idx[l * NPORT + (8 * lane + 2 * j)];
                float th = thetas[m], ph = phis[m];
                mzi(cosf(th) * ATTEN, sinf(th) * ATTEN, cosf(ph), sinf(ph),
                    2 * j, 2 * j + 1);
            }
        } else {
            float hr = __shfl_down(sr[0], 1);
            float hi = __shfl_down(si[0], 1);
#pragma unroll
            for (int j = 0; j < 3; ++j) {
                int m = mzi_idx[l * NPORT + (8 * lane + 2 * j + 1)];
                float th = thetas[m], ph = phis[m];
                mzi(cosf(th) * ATTEN, sinf(th) * ATTEN, cosf(ph), sinf(ph),
                    2 * j + 1, 2 * j + 2);
            }
            float ct = 1.f, st = 0.f, er = 1.f, ei = 0.f;
            if (lane < 63) {
                int m = mzi_idx[l * NPORT + (8 * lane + 7)];
                float th = thetas[m], ph = phis[m];
                ct = cosf(th) * ATTEN; st = sinf(th) * ATTEN;
                er = cosf(ph); ei = sinf(ph);
            }
            float ur = ct * sr[7] + st * hr;
            float ui = ct * si[7] + st * hi;
            float lr = ct * hr - st * sr[7];
            float li = ct * hi - st * si[7];
            sr[7] = er * ur - ei * ui;
            si[7] = er * ui + ei * ur;
            float rlr = __shfl_up(lr, 1);
            float rli = __shfl_up(li, 1);
            sr[0] = (lane > 0) ? rlr : sr[0];
            si[0] = (lane > 0) ? rli : si[0];
        }
    }

    float4 o0 = make_float4(sr[0] * sr[0] + si[0] * si[0],
                            sr[1] * sr[1] + si[1] * si[1],
                            sr[2] * sr[2] + si[2] * si[2],
                            sr[3] * sr[3] + si[3] * si[3]);
    float4 o1 = make_float4(sr[4] * sr[4] + si[4] * si[4],
                            sr[5] * sr[5] + si[5] * si[5],
                            sr[6] * sr[6] + si[6] * si[6],
                            sr[7] * sr[7] + si[7] * si[7]);
    float4* op = (float4*)(out + (size_t)row * NPORT) + lane * 2;
    op[0] = o0;
    op[1] = o1;
}

// ---------------------------------------------------------------------------
// Inputs (setup_inputs order): x[B*N] f32, thetas[M] f32, phis[M] f32,
// partner[L*N] i32 (unused), mzi_idx[L*N] i32, role[L*N] i32 (unused).
// ---------------------------------------------------------------------------
extern "C" void kernel_launch(void* const* d_in, const int* in_sizes, int n_in,
                              void* d_out, int out_size, void* d_ws,
                              size_t ws_size, hipStream_t stream) {
    const float* x       = (const float*)d_in[0];
    const float* thetas  = (const float*)d_in[1];
    const float* phis    = (const float*)d_in[2];
    const int*   mzi_idx = (const int*)d_in[4];
    float*       out     = (float*)d_out;

    int B = in_sizes[0] / NPORT;

    const size_t table_bytes = (size_t)NPAIR * PPL * 64 * sizeof(float4); // 2 MiB
    if (ws_size >= table_bytes) {
        float4* table = (float4*)d_ws;
        int nthreads = NPAIR * PPL * 64;
        coeff_kernel<<<(nthreads + 255) / 256, 256, 0, stream>>>(
            thetas, phis, mzi_idx, table);
        int nblk = (B + 1) / 2;
        mesh_kernel<<<nblk, 128, 0, stream>>>(x, table, out, B);
    } else {
        mesh_fallback<<<B, 64, 0, stream>>>(x, thetas, phis, mzi_idx, out);
    }
}

// Round 5
// 166.123 us; speedup vs baseline: 1.2132x; 1.2132x over previous
//
#include <hip/hip_runtime.h>
#include <math.h>

// Problem constants (N=512 Clements mesh, L=512 layers, fixed by reference).
#define NPORT  512
#define NLAYER 512
#define NPAIR  256                      // even/odd layer pairs
#define CHUNK  4                        // layer-pairs per LDS stage
#define NCHUNK (NPAIR / CHUNK)          // 64 chunks
#define PPL    8                        // coefficient planes per pair
#define PLANES (CHUNK * PPL)            // 32 planes per chunk (32 KB)
#define ATTEN  0.9772372209558107f      // sqrt(10^(-0.2/10))

// Async global->LDS DMA, 16B per lane: LDS dst = uniform base + lane*16.
__device__ __forceinline__ void load_lds16(const float4* g, void* l) {
    __builtin_amdgcn_global_load_lds(
        (const __attribute__((address_space(1))) void*)g,
        (__attribute__((address_space(3))) void*)l, 16, 0, 0);
}

// Lane-shift shuffles via DPP (VALU pipe, no lgkm counter!). This keeps the
// odd-layer boundary exchange OFF the in-order LDS queue so it cannot drain
// the next pair's ds_read prefetch (the round-3 serializer).
// wave_shr:1 (0x138): lane i <- lane i-1 (shfl_up);  lane 0 keeps old.
// wave_shl:1 (0x130): lane i <- lane i+1 (shfl_down); lane 63 keeps old.
__device__ __forceinline__ float dpp_up1(float x) {
    int r = __builtin_amdgcn_update_dpp(__float_as_int(x), __float_as_int(x),
                                        0x138, 0xF, 0xF, false);
    return __int_as_float(r);
}
__device__ __forceinline__ float dpp_down1(float x) {
    int r = __builtin_amdgcn_update_dpp(__float_as_int(x), __float_as_int(x),
                                        0x130, 0xF, 0xF, false);
    return __int_as_float(r);
}

// ---------------------------------------------------------------------------
// Coefficient table: per layer-pair p, 8 planes of 64 float4 (one per lane):
//   planes 0..3: even layer 2p,  lane t slot 4t+j (ports 8t+2j, 8t+2j+1)
//   planes 4..7: odd  layer 2p+1, lane t slot 4t+j (ports 8t+2j+1, 8t+2j+2)
// float4 = {cos(th)*A, sin(th)*A, cos(ph), sin(ph)}; invalid slot (odd,255)
// = identity {1,0,1,0}. The odd-layer LEFT-crossing coefficient for lane t
// (slot 4t-1) is lane t-1's plane-7 value (obtained via dpp_up1).
// ---------------------------------------------------------------------------
__global__ void coeff_kernel(const float* __restrict__ thetas,
                             const float* __restrict__ phis,
                             const int*   __restrict__ mzi_idx,
                             float4*      __restrict__ table) {
    int tid = blockIdx.x * blockDim.x + threadIdx.x;   // 0 .. NPAIR*8*64-1
    if (tid >= NPAIR * PPL * 64) return;
    int lane  = tid & 63;
    int plane = (tid >> 6) & 7;
    int p     = tid >> 9;

    int layer, slot, port_i;
    bool valid;
    if (plane < 4) {                    // even layer
        layer  = 2 * p;
        slot   = 4 * lane + plane;
        port_i = 2 * slot;
        valid  = true;
    } else {                            // odd layer local slots
        layer  = 2 * p + 1;
        slot   = 4 * lane + (plane - 4);
        port_i = 2 * slot + 1;
        valid  = (2 * slot + 2) < NPORT;   // slot 255 -> ports 511/512
    }

    float4 c = make_float4(1.f, 0.f, 1.f, 0.f);
    if (valid) {
        int m  = mzi_idx[layer * NPORT + port_i];
        float th = thetas[m], ph = phis[m];
        c.x = cosf(th) * ATTEN;
        c.y = sinf(th) * ATTEN;
        c.z = cosf(ph);
        c.w = sinf(ph);
    }
    table[(size_t)(p * PPL + plane) * 64 + lane] = c;
}

// ---------------------------------------------------------------------------
// Mesh propagation. 256 threads = 4 waves/block, one batch row per wave;
// lane t holds ports 8t..8t+7 (complex) in registers. 256 blocks = 1/CU.
// Chunk of 4 layer-pairs staged in LDS via global_load_lds double-buffered
// across two distinct __shared__ arrays; consumed with a 1-pair-deep
// ds_read_b128 rotation. All cross-lane traffic in compute is DPP (VALU),
// so the only lgkm ops are the coefficient reads themselves -> the rotation
// genuinely overlaps LDS reads with VALU.
// ---------------------------------------------------------------------------
struct PairCoef {
    float4 e[4];   // even-layer slots
    float4 o[4];   // odd-layer local slots
};

__global__ __launch_bounds__(256, 1)
void mesh_kernel(const float*  __restrict__ x,
                 const float4* __restrict__ table,
                 float*        __restrict__ out,
                 int B) {
    __shared__ float4 bufA[PLANES][64];   // 32 KB
    __shared__ float4 bufB[PLANES][64];   // 32 KB

    const int lane = threadIdx.x & 63;
    const int wid  = threadIdx.x >> 6;    // 0..3
    const int row  = blockIdx.x * 4 + wid;
    const bool live = row < B;

    // Load 8 consecutive real inputs -> complex state (im = 0).
    const float4* xr =
        (const float4*)(x + (size_t)(live ? row : 0) * NPORT) + lane * 2;
    float4 xa = xr[0], xb = xr[1];
    float sr[8] = {xa.x, xa.y, xa.z, xa.w, xb.x, xb.y, xb.z, xb.w};
    float si[8] = {0.f, 0.f, 0.f, 0.f, 0.f, 0.f, 0.f, 0.f};

    // DMA chunk c's 32 planes into buf; wave w takes planes 8w..8w+7.
    auto stage = [&](int c, float4 (*buf)[64]) {
        const float4* g = table + (size_t)c * (PLANES * 64) + lane;
#pragma unroll
        for (int k = 0; k < PPL; ++k) {
            int pl = wid * PPL + k;
            load_lds16(g + pl * 64, (void*)&buf[pl][0]);
        }
    };

    // One MZI, both ports lane-local; upper port gets the phase.
    auto mzi = [&](const float4 c, int p0, int p1) {
        float ct = c.x, st = c.y, er = c.z, ei = c.w;
        float ur = ct * sr[p0] + st * sr[p1];
        float ui = ct * si[p0] + st * si[p1];
        float lr = ct * sr[p1] - st * sr[p0];
        float li = ct * si[p1] - st * si[p0];
        sr[p0] = er * ur - ei * ui;
        si[p0] = er * ui + ei * ur;
        sr[p1] = lr;
        si[p1] = li;
    };

    auto computePair = [&](const PairCoef& b) {
        // Even layer: ports (2j, 2j+1), all lane-local.
#pragma unroll
        for (int j = 0; j < 4; ++j) mzi(b.e[j], 2 * j, 2 * j + 1);

        // Odd layer. All 6 cross-lane moves via DPP on OLD values (VALU pipe).
        float hr = dpp_down1(sr[0]);      // right neighbor's port 8t+8
        float hi = dpp_down1(si[0]);
        float gr = dpp_up1(sr[7]);        // left neighbor's port 8t-1
        float gi = dpp_up1(si[7]);
        float lc = dpp_up1(b.o[3].x);     // left-crossing ct (slot 4t-1)
        float ls = dpp_up1(b.o[3].y);     // left-crossing st
        float ct4 = (lane > 0) ? lc : 1.f;  // lane 0: port 0 passthrough
        float st4 = (lane > 0) ? ls : 0.f;

        // 3 internal MZIs: ports (2j+1, 2j+2).
#pragma unroll
        for (int j = 0; j < 3; ++j) mzi(b.o[j], 2 * j + 1, 2 * j + 2);

        // Right crossing (upper = local port 7, lower = h): keep upper+phase.
        // Lane 63: slot 255 identity {1,0} -> sr7 passthrough, h unused (x0).
        {
            float ct = b.o[3].x, st = b.o[3].y, er = b.o[3].z, ei = b.o[3].w;
            float ur = ct * sr[7] + st * hr;
            float ui = ct * si[7] + st * hi;
            sr[7] = er * ur - ei * ui;
            si[7] = er * ui + ei * ur;
        }
        // Left crossing (upper = g, lower = local port 0): keep lower.
        {
            float lr = ct4 * sr[0] - st4 * gr;
            float li = ct4 * si[0] - st4 * gi;
            sr[0] = lr;
            si[0] = li;
        }
    };

    auto readPair = [&](const float4 (*buf)[64], int pp) {
        PairCoef b;
#pragma unroll
        for (int j = 0; j < 4; ++j) b.e[j] = buf[pp * PPL + j][lane];
#pragma unroll
        for (int j = 0; j < 4; ++j) b.o[j] = buf[pp * PPL + 4 + j][lane];
        return b;
    };

    // 1-pair-deep rotation: issue pair p+1's 8 ds_read_b128, compute pair p.
    // With DPP shuffles there are no other lgkm ops, so the waitcnt before
    // pair p+1's compute covers reads issued ~200 VALU cycles earlier.
    auto computeChunk = [&](const float4 (*buf)[64]) {
        PairCoef A = readPair(buf, 0);
#pragma unroll
        for (int pp = 0; pp < CHUNK; ++pp) {
            PairCoef Bn;
            if (pp + 1 < CHUNK) Bn = readPair(buf, pp + 1);
            computePair(A);
            if (pp + 1 < CHUNK) A = Bn;
        }
    };

    stage(0, bufA);
    __syncthreads();

#pragma unroll 1
    for (int c = 0; c < NCHUNK; c += 2) {
        if (c + 1 < NCHUNK) stage(c + 1, bufB);
        computeChunk(bufA);
        __syncthreads();
        if (c + 2 < NCHUNK) stage(c + 2, bufA);
        computeChunk(bufB);
        __syncthreads();
    }

    // Photodetection: |E|^2, vectorized store.
    if (live) {
        float4 o0 = make_float4(sr[0] * sr[0] + si[0] * si[0],
                                sr[1] * sr[1] + si[1] * si[1],
                                sr[2] * sr[2] + si[2] * si[2],
                                sr[3] * sr[3] + si[3] * si[3]);
        float4 o1 = make_float4(sr[4] * sr[4] + si[4] * si[4],
                                sr[5] * sr[5] + si[5] * si[5],
                                sr[6] * sr[6] + si[6] * si[6],
                                sr[7] * sr[7] + si[7] * si[7]);
        float4* op = (float4*)(out + (size_t)row * NPORT) + lane * 2;
        op[0] = o0;
        op[1] = o1;
    }
}

// ---------------------------------------------------------------------------
// Fallback (ws too small for the table): trig inline, slow but correct.
// ---------------------------------------------------------------------------
__global__ __launch_bounds__(64)
void mesh_fallback(const float* __restrict__ x,
                   const float* __restrict__ thetas,
                   const float* __restrict__ phis,
                   const int*   __restrict__ mzi_idx,
                   float*       __restrict__ out) {
    const int lane = threadIdx.x;
    const int row  = blockIdx.x;

    const float4* xr = (const float4*)(x + (size_t)row * NPORT) + lane * 2;
    float4 xa = xr[0], xb = xr[1];
    float sr[8] = {xa.x, xa.y, xa.z, xa.w, xb.x, xb.y, xb.z, xb.w};
    float si[8] = {0.f, 0.f, 0.f, 0.f, 0.f, 0.f, 0.f, 0.f};

    auto mzi = [&](float ct, float st, float er, float ei, int p0, int p1) {
        float ur = ct * sr[p0] + st * sr[p1];
        float ui = ct * si[p0] + st * si[p1];
        float lr = ct * sr[p1] - st * sr[p0];
        float li = ct * si[p1] - st * si[p0];
        sr[p0] = er * ur - ei * ui;
        si[p0] = er * ui + ei * ur;
        sr[p1] = lr;
        si[p1] = li;
    };

    for (int l = 0; l < NLAYER; ++l) {
        if ((l & 1) == 0) {
#pragma unroll
            for (int j = 0; j < 4; ++j) {
                int m = mzi_idx[l * NPORT + (8 * lane + 2 * j)];
                float th = thetas[m], ph = phis[m];
                mzi(cosf(th) * ATTEN, sinf(th) * ATTEN, cosf(ph), sinf(ph),
                    2 * j, 2 * j + 1);
            }
        } else {
            float hr = __shfl_down(sr[0], 1);
            float hi = __shfl_down(si[0], 1);
#pragma unroll
            for (int j = 0; j < 3; ++j) {
                int m = mzi_idx[l * NPORT + (8 * lane + 2 * j + 1)];
                float th = thetas[m], ph = phis[m];
                mzi(cosf(th) * ATTEN, sinf(th) * ATTEN, cosf(ph), sinf(ph),
                    2 * j + 1, 2 * j + 2);
            }
            float ct = 1.f, st = 0.f, er = 1.f, ei = 0.f;
            if (lane < 63) {
                int m = mzi_idx[l * NPORT + (8 * lane + 7)];
                float th = thetas[m], ph = phis[m];
                ct = cosf(th) * ATTEN; st = sinf(th) * ATTEN;
                er = cosf(ph); ei = sinf(ph);
            }
            float ur = ct * sr[7] + st * hr;
            float ui = ct * si[7] + st * hi;
            float lr = ct * hr - st * sr[7];
            float li = ct * hi - st * si[7];
            sr[7] = er * ur - ei * ui;
            si[7] = er * ui + ei * ur;
            float rlr = __shfl_up(lr, 1);
            float rli = __shfl_up(li, 1);
            sr[0] = (lane > 0) ? rlr : sr[0];
            si[0] = (lane > 0) ? rli : si[0];
        }
    }

    float4 o0 = make_float4(sr[0] * sr[0] + si[0] * si[0],
                            sr[1] * sr[1] + si[1] * si[1],
                            sr[2] * sr[2] + si[2] * si[2],
                            sr[3] * sr[3] + si[3] * si[3]);
    float4 o1 = make_float4(sr[4] * sr[4] + si[4] * si[4],
                            sr[5] * sr[5] + si[5] * si[5],
                            sr[6] * sr[6] + si[6] * si[6],
                            sr[7] * sr[7] + si[7] * si[7]);
    float4* op = (float4*)(out + (size_t)row * NPORT) + lane * 2;
    op[0] = o0;
    op[1] = o1;
}

// ---------------------------------------------------------------------------
// Inputs (setup_inputs order): x[B*N] f32, thetas[M] f32, phis[M] f32,
// partner[L*N] i32 (unused), mzi_idx[L*N] i32, role[L*N] i32 (unused).
// ---------------------------------------------------------------------------
extern "C" void kernel_launch(void* const* d_in, const int* in_sizes, int n_in,
                              void* d_out, int out_size, void* d_ws,
                              size_t ws_size, hipStream_t stream) {
    const float* x       = (const float*)d_in[0];
    const float* thetas  = (const float*)d_in[1];
    const float* phis    = (const float*)d_in[2];
    const int*   mzi_idx = (const int*)d_in[4];
    float*       out     = (float*)d_out;

    int B = in_sizes[0] / NPORT;

    const size_t table_bytes = (size_t)NPAIR * PPL * 64 * sizeof(float4); // 2 MiB
    if (ws_size >= table_bytes) {
        float4* table = (float4*)d_ws;
        int nthreads = NPAIR * PPL * 64;
        coeff_kernel<<<(nthreads + 255) / 256, 256, 0, stream>>>(
            thetas, phis, mzi_idx, table);
        int nblk = (B + 3) / 4;
        mesh_kernel<<<nblk, 256, 0, stream>>>(x, table, out, B);
    } else {
        mesh_fallback<<<B, 64, 0, stream>>>(x, thetas, phis, mzi_idx, out);
    }
}